// Round 8
// baseline (203.893 us; speedup 1.0000x reference)
//
#include <hip/hip_runtime.h>
#include <math.h>

// Problem constants
#define Bn   8
#define Cn   128
#define Hn   64
#define Wn   64
#define HWn  4096
#define Un   8
#define Ln   10
#define HIDn 128

// d_out layout (float offsets): final, cls_logits, l2_reg, top_i, lb_loss
#define OUT_FINAL 0
#define OUT_CLS   4194304
#define OUT_L2    4194384
#define OUT_TOPI  4194385
#define OUT_LB    4194401

// ws layout (float offsets)
#define WS_POOLED 0                      // [1024]
#define WS_STR    1024                   // [1024*9] S,R0,R63,C0,C63,c00,c0r,cb0,cbr
#define WS_TOPI   10240                  // int[16]
#define WS_GSEL   10256                  // [16]
#define WS_BIASC  10272                  // [1024]
#define WS_L2P    11296                  // [12]
#define WS_GSUM   11308                  // [64] conv-mean-sum per (b,u)
#define WS_BSUM   11372                  // [8]
#define WS_H1     11380                  // [1024]
#define WS_H2     12404                  // [1024]
#define WS_H3     13428                  // [512]
#define WS_FEAT   13940                  // [512]
#define WS_GATE   14452                  // [64] full gate matrix
#define WS_BAR    14516                  // unsigned[8] spin-barrier counters
#define WS_W9P    14524                  // [64][1152] w9 partials
#define WS_XT     88252                  // bf16 xt[8][64][64][128]
#define WS_WCOMB  2185404                // bf16 wcomb[8][128][9][128]

#define NOISE_PARTITIONABLE 1
#define RGRID 80u

typedef __attribute__((ext_vector_type(8))) short bf16x8;
typedef __attribute__((ext_vector_type(4))) float f32x4;

__device__ __forceinline__ unsigned short f2bf(float f) {
    unsigned u = __float_as_uint(f);
    unsigned r = (u + 0x7fffu + ((u >> 16) & 1u)) >> 16;
    return (unsigned short)r;
}

// device-scope grid barrier (all RGRID blocks co-resident; counters zeroed by
// prep_kernel which precedes on-stream)
__device__ __forceinline__ void grid_bar(unsigned* bar, int slot) {
    __syncthreads();
    if (threadIdx.x == 0) {
        unsigned* c = bar + slot;
        __hip_atomic_fetch_add(c, 1u, __ATOMIC_ACQ_REL, __HIP_MEMORY_SCOPE_AGENT);
        while (__hip_atomic_load(c, __ATOMIC_ACQUIRE, __HIP_MEMORY_SCOPE_AGENT) < RGRID)
            __builtin_amdgcn_s_sleep(1);
    }
    __syncthreads();
}

// ---------------- jax threefry2x32 noise (key=42, shape (8,8)) --------------
__device__ __forceinline__ unsigned rotl32(unsigned x, int d) {
    return (x << d) | (x >> (32 - d));
}

__device__ __forceinline__ void threefry2x32(unsigned k1, unsigned k2,
                                             unsigned c0, unsigned c1,
                                             unsigned* o0, unsigned* o1) {
    unsigned ks0 = k1, ks1 = k2, ks2 = k1 ^ k2 ^ 0x1BD11BDAu;
    unsigned ksa[3] = {ks0, ks1, ks2};
    const int rot[2][4] = {{13, 15, 26, 6}, {17, 29, 16, 24}};
    unsigned x0 = c0 + ks0, x1 = c1 + ks1;
    #pragma unroll
    for (int s = 0; s < 5; ++s) {
        #pragma unroll
        for (int q = 0; q < 4; ++q) {
            x0 += x1;
            x1 = rotl32(x1, rot[s & 1][q]);
            x1 ^= x0;
        }
        x0 += ksa[(s + 1) % 3];
        x1 += ksa[(s + 2) % 3] + (unsigned)(s + 1);
    }
    *o0 = x0;
    *o1 = x1;
}

__device__ float jax_noise_elem(int i) {
    unsigned o0, o1, bits;
#if NOISE_PARTITIONABLE
    threefry2x32(0u, 42u, 0u, (unsigned)i, &o0, &o1);
    bits = o0 ^ o1;
#else
    {
        int second = (i >= 32);
        unsigned j = (unsigned)(second ? i - 32 : i);
        threefry2x32(0u, 42u, j, j + 32u, &o0, &o1);
        bits = second ? o1 : o0;
    }
#endif
    unsigned fb = (bits >> 9) | 0x3f800000u;
    float f = __uint_as_float(fb) - 1.0f;
    const float lo = __uint_as_float(0xBF7FFFFFu);
    float u = f * (1.0f - lo) + lo;
    u = fmaxf(lo, u);
    float w = -log1pf(-u * u);
    float p;
    if (w < 5.0f) {
        w = w - 2.5f;
        p = 2.81022636e-08f;
        p = fmaf(p, w, 3.43273939e-07f);
        p = fmaf(p, w, -3.5233877e-06f);
        p = fmaf(p, w, -4.39150654e-06f);
        p = fmaf(p, w, 0.00021858087f);
        p = fmaf(p, w, -0.00125372503f);
        p = fmaf(p, w, -0.00417768164f);
        p = fmaf(p, w, 0.246640727f);
        p = fmaf(p, w, 1.50140941f);
    } else {
        w = sqrtf(w) - 3.0f;
        p = -0.000200214257f;
        p = fmaf(p, w, 0.000100950558f);
        p = fmaf(p, w, 0.00134934322f);
        p = fmaf(p, w, -0.00367342844f);
        p = fmaf(p, w, 0.00573950773f);
        p = fmaf(p, w, -0.0076224613f);
        p = fmaf(p, w, 0.00943887047f);
        p = fmaf(p, w, 1.00167406f);
        p = fmaf(p, w, 2.83297682f);
    }
    float n = 1.41421356237309515f * (p * u);
    return n * 0.01f;
}

// -------- kernel 1: xprep(512) + pool/strips(1024) + w9(64) + l2(12) -------
__global__ __launch_bounds__(256) void prep_kernel(
    const float* __restrict__ x, const float* __restrict__ cw,
    const float* __restrict__ W1, const float* __restrict__ b1,
    const float* __restrict__ W2, const float* __restrict__ b2,
    const float* __restrict__ W3, const float* __restrict__ b3,
    const float* __restrict__ W4, const float* __restrict__ b4,
    const float* __restrict__ Wu, const float* __restrict__ bu,
    const float* __restrict__ Wc, const float* __restrict__ bc,
    float* __restrict__ ws) {
    __shared__ float smem[8256];
    int bid = blockIdx.x;
    int tid = threadIdx.x;

    if (bid < 512) {
        // ---- x transpose to channel-last bf16: xt[b][y][x][cin] ----
        int b = bid >> 6, y = bid & 63;
        #pragma unroll
        for (int k = 0; k < 32; ++k) {
            int cin = (tid >> 6) + (k << 2);
            int xcol = tid & 63;
            smem[xcol * 129 + cin] =
                x[(((size_t)b * 128 + cin) << 12) + (y << 6) + xcol];
        }
        __syncthreads();
        unsigned short* xtp = (unsigned short*)(ws + WS_XT);
        #pragma unroll
        for (int i = 0; i < 4; ++i) {
            int op = tid + (i << 8);
            int px = op >> 4, part = op & 15;
            const float* src = smem + px * 129 + part * 8;
            uint4 u;
            u.x = (unsigned)f2bf(src[0]) | ((unsigned)f2bf(src[1]) << 16);
            u.y = (unsigned)f2bf(src[2]) | ((unsigned)f2bf(src[3]) << 16);
            u.z = (unsigned)f2bf(src[4]) | ((unsigned)f2bf(src[5]) << 16);
            u.w = (unsigned)f2bf(src[6]) | ((unsigned)f2bf(src[7]) << 16);
            *(uint4*)(xtp + (((((size_t)b * 64 + y) * 64 + px) << 7) + (part << 3))) = u;
        }
    } else if (bid < 1536) {
        // ---- avg pool + border strips + corners per (b,cin) ----
        int bc_ = bid - 512;
        const float4* p4 = (const float4*)(x + (size_t)bc_ * HWn);
        float vals[5] = {0.f, 0.f, 0.f, 0.f, 0.f};  // S,R0,R63,C0,C63
        #pragma unroll
        for (int it = 0; it < 4; ++it) {
            int i = tid + it * 256;
            float4 v = p4[i];
            float s4 = v.x + v.y + v.z + v.w;
            vals[0] += s4;
            if (i < 16) vals[1] += s4;
            if (i >= 1008) vals[2] += s4;
            if ((i & 15) == 0) vals[3] += v.x;
            if ((i & 15) == 15) vals[4] += v.w;
            if (i == 0) ws[WS_STR + bc_ * 9 + 5] = v.x;
            if (i == 15) ws[WS_STR + bc_ * 9 + 6] = v.w;
            if (i == 1008) ws[WS_STR + bc_ * 9 + 7] = v.x;
            if (i == 1023) ws[WS_STR + bc_ * 9 + 8] = v.w;
        }
        #pragma unroll
        for (int q = 0; q < 5; ++q)
            #pragma unroll
            for (int off = 32; off > 0; off >>= 1)
                vals[q] += __shfl_xor(vals[q], off);
        int wave = tid >> 6, lane = tid & 63;
        if (lane == 0) {
            #pragma unroll
            for (int q = 0; q < 5; ++q) smem[wave * 5 + q] = vals[q];
        }
        __syncthreads();
        if (tid < 5) {
            float o = smem[tid] + smem[5 + tid] + smem[10 + tid] + smem[15 + tid];
            ws[WS_STR + bc_ * 9 + tid] = o;
            if (tid == 0) ws[WS_POOLED + bc_] = o * (1.0f / HWn);
        }
    } else if (bid < 1600) {
        // ---- w9 partials: block (u,g) sums couts g*16..g*16+15 ----
        int idx = bid - 1536;
        int u = idx >> 3, g = idx & 7;
        if (idx == 0 && tid < 8) ((unsigned*)(ws + WS_BAR))[tid] = 0u;
        const float* base = cw + (size_t)u * 147456 + (size_t)g * 18432;
        float a0 = 0.f, a1 = 0.f, a2 = 0.f, a3 = 0.f, a4 = 0.f;
        #pragma unroll
        for (int cout = 0; cout < 16; ++cout) {
            const float* row = base + (size_t)cout * 1152;
            a0 += row[tid];
            a1 += row[tid + 256];
            a2 += row[tid + 512];
            a3 += row[tid + 768];
            if (tid < 128) a4 += row[tid + 1024];
        }
        float* dst = ws + WS_W9P + (size_t)idx * 1152;
        dst[tid] = a0;
        dst[tid + 256] = a1;
        dst[tid + 512] = a2;
        dst[tid + 768] = a3;
        if (tid < 128) dst[tid + 1024] = a4;
    } else {
        // ---- l2 sumsq partials for the 12 router params ----
        int idx = bid - 1600;
        const float* ptab[12] = {W1, b1, W2, b2, W3, b3, W4, b4, Wu, bu, Wc, bc};
        const int ntab[12] = {16384, 128, 16384, 128, 8192, 64, 4096, 64, 512, 8, 640, 10};
        const float* p = ptab[idx];
        int n = ntab[idx];
        float s = 0.f;
        for (int i = tid; i < n; i += 256) { float v = p[i]; s = fmaf(v, v, s); }
        #pragma unroll
        for (int off = 32; off > 0; off >>= 1) s += __shfl_xor(s, off);
        int wave = tid >> 6, lane = tid & 63;
        if (lane == 0) smem[wave] = s;
        __syncthreads();
        if (tid == 0) ws[WS_L2P + idx] = smem[0] + smem[1] + smem[2] + smem[3];
    }
}

// -------- kernel 2: fused router (gsum || mlp, then score/gate/biasc) ------
// 80 blocks, spin barriers; replaces 6 serial launches (gsum, mlp x4,
// score_gate) whose per-launch overhead dominated their ~3 us of work each
__global__ __launch_bounds__(256) void router_fused_kernel(
    const float* __restrict__ W1, const float* __restrict__ b1,
    const float* __restrict__ W2, const float* __restrict__ b2,
    const float* __restrict__ W3, const float* __restrict__ b3,
    const float* __restrict__ W4, const float* __restrict__ b4,
    const float* __restrict__ Wu, const float* __restrict__ bu,
    const float* __restrict__ Wc, const float* __restrict__ bc,
    const float* __restrict__ cb,
    float* __restrict__ ws, float* __restrict__ out) {
    __shared__ float sh[1216];
    int bid = blockIdx.x;
    int tid = threadIdx.x;
    unsigned* bar = (unsigned*)(ws + WS_BAR);

    // ---- stage A: blocks 0-15 MLP layer1; blocks 16-79 gsum ----
    if (bid < 16) {
        for (int i = tid; i < 1024; i += 256) sh[i] = ws[WS_POOLED + i];
        __syncthreads();
        int r = tid >> 5, l = tid & 31;
        int j = bid * 8 + r;
        float4 w = ((const float4*)(W1 + j * 128))[l];
        float bj = b1[j];
        #pragma unroll
        for (int b = 0; b < 8; ++b) {
            const float* sp = sh + b * 128 + l * 4;
            float s = w.x * sp[0] + w.y * sp[1] + w.z * sp[2] + w.w * sp[3];
            s += __shfl_xor(s, 16, 32); s += __shfl_xor(s, 8, 32);
            s += __shfl_xor(s, 4, 32);  s += __shfl_xor(s, 2, 32);
            s += __shfl_xor(s, 1, 32);
            if (l == 0) ws[WS_H1 + b * 128 + j] = fmaxf(s + bj, 0.f);
        }
    } else {
        int idx = bid - 16;              // b*8 + u
        int b = idx >> 3, u = idx & 7;
        float* T = sh;
        float* red = sh + 1152;
        if (tid < 128) {
            const float* st = ws + WS_STR + (b * 128 + tid) * 9;
            float S = st[0], R0 = st[1], R63 = st[2], C0 = st[3], C63 = st[4];
            float c00 = st[5], c0r = st[6], cb0 = st[7], cbr = st[8];
            float Rex[3] = {R63, 0.f, R0};
            float Cex[3] = {C63, 0.f, C0};
            float crn[3][3] = {{cbr, 0.f, cb0}, {0.f, 0.f, 0.f}, {c0r, 0.f, c00}};
            #pragma unroll
            for (int ky = 0; ky < 3; ++ky)
                #pragma unroll
                for (int kx = 0; kx < 3; ++kx)
                    T[tid * 9 + ky * 3 + kx] = S - Rex[ky] - Cex[kx] + crn[ky][kx];
        }
        __syncthreads();
        float s = 0.f;
        #pragma unroll
        for (int g = 0; g < 8; ++g) {
            const float* row = ws + WS_W9P + (size_t)((u << 3) + g) * 1152;
            #pragma unroll
            for (int i = 0; i < 4; ++i)
                s = fmaf(row[tid + i * 256], T[tid + i * 256], s);
            if (tid < 128) s = fmaf(row[tid + 1024], T[tid + 1024], s);
        }
        #pragma unroll
        for (int off = 32; off > 0; off >>= 1) s += __shfl_xor(s, off);
        int wave = tid >> 6, lane = tid & 63;
        if (lane == 0) red[wave] = s;
        __syncthreads();
        if (tid == 0) ws[WS_GSUM + idx] = red[0] + red[1] + red[2] + red[3];
        if (b == 0) {
            float t2 = (tid < 128) ? cb[u * 128 + tid] : 0.f;
            #pragma unroll
            for (int off = 32; off > 0; off >>= 1) t2 += __shfl_xor(t2, off);
            if (lane == 0) red[wave] = t2;
            __syncthreads();
            if (tid == 0) ws[WS_BSUM + u] = red[0] + red[1] + red[2] + red[3];
        }
    }
    grid_bar(bar, 0);

    // ---- stage B: layer2 ----
    if (bid < 16) {
        for (int i = tid; i < 1024; i += 256) sh[i] = ws[WS_H1 + i];
        __syncthreads();
        int r = tid >> 5, l = tid & 31;
        int j = bid * 8 + r;
        float4 w = ((const float4*)(W2 + j * 128))[l];
        float bj = b2[j];
        #pragma unroll
        for (int b = 0; b < 8; ++b) {
            const float* sp = sh + b * 128 + l * 4;
            float s = w.x * sp[0] + w.y * sp[1] + w.z * sp[2] + w.w * sp[3];
            s += __shfl_xor(s, 16, 32); s += __shfl_xor(s, 8, 32);
            s += __shfl_xor(s, 4, 32);  s += __shfl_xor(s, 2, 32);
            s += __shfl_xor(s, 1, 32);
            if (l == 0) ws[WS_H2 + b * 128 + j] = fmaxf(s + bj, 0.f);
        }
    }
    grid_bar(bar, 1);

    // ---- stage C: layer3 (64 rows, 8 blocks) ----
    if (bid < 8) {
        for (int i = tid; i < 1024; i += 256) sh[i] = ws[WS_H2 + i];
        __syncthreads();
        int r = tid >> 5, l = tid & 31;
        int j = bid * 8 + r;
        float4 w = ((const float4*)(W3 + j * 128))[l];
        float bj = b3[j];
        #pragma unroll
        for (int b = 0; b < 8; ++b) {
            const float* sp = sh + b * 128 + l * 4;
            float s = w.x * sp[0] + w.y * sp[1] + w.z * sp[2] + w.w * sp[3];
            s += __shfl_xor(s, 16, 32); s += __shfl_xor(s, 8, 32);
            s += __shfl_xor(s, 4, 32);  s += __shfl_xor(s, 2, 32);
            s += __shfl_xor(s, 1, 32);
            if (l == 0) ws[WS_H3 + b * 64 + j] = fmaxf(s + bj, 0.f);
        }
    }
    grid_bar(bar, 2);

    // ---- stage D: layer4 (64 rows, K=64, no relu) ----
    if (bid < 8) {
        for (int i = tid; i < 512; i += 256) sh[i] = ws[WS_H3 + i];
        __syncthreads();
        int r = tid >> 5, l = tid & 31;
        int j = bid * 8 + r;
        float2 w = ((const float2*)(W4 + j * 64))[l];
        float bj = b4[j];
        #pragma unroll
        for (int b = 0; b < 8; ++b) {
            const float* sp = sh + b * 64 + l * 2;
            float s = w.x * sp[0] + w.y * sp[1];
            s += __shfl_xor(s, 16, 32); s += __shfl_xor(s, 8, 32);
            s += __shfl_xor(s, 4, 32);  s += __shfl_xor(s, 2, 32);
            s += __shfl_xor(s, 1, 32);
            if (l == 0) ws[WS_FEAT + b * 64 + j] = s + bj;
        }
    }
    grid_bar(bar, 3);

    // ---- stage E: block 0: scores, logits, noise, topk, lb, l2, gate ----
    if (bid == 0) {
        float* feat = sh;            // 512
        float* scores = sh + 512;    // 64
        float* noise = sh + 576;     // 64
        float* gate = sh + 640;      // 64
        int* topi = (int*)(sh + 704);
        int grp = tid >> 4, l = tid & 15;
        for (int i = tid; i < 512; i += 256) feat[i] = ws[WS_FEAT + i];
        __syncthreads();
        if (tid < 64) noise[tid] = jax_noise_elem(tid);
        if (grp < 8) {
            int j = grp;
            float4 wa = ((const float4*)(Wu + j * 64))[l];
            float bj = bu[j];
            #pragma unroll
            for (int b = 0; b < 8; ++b) {
                const float* sp = feat + b * 64 + l * 4;
                float s = wa.x * sp[0] + wa.y * sp[1] + wa.z * sp[2] + wa.w * sp[3];
                s += __shfl_xor(s, 8, 16); s += __shfl_xor(s, 4, 16);
                s += __shfl_xor(s, 2, 16); s += __shfl_xor(s, 1, 16);
                if (l == 0) scores[b * 8 + j] = s + bj;
            }
        }
        if (grp < 10) {
            int j = grp;
            float4 wa = ((const float4*)(Wc + j * 64))[l];
            float bj = bc[j];
            #pragma unroll
            for (int b = 0; b < 8; ++b) {
                const float* sp = feat + b * 64 + l * 4;
                float s = wa.x * sp[0] + wa.y * sp[1] + wa.z * sp[2] + wa.w * sp[3];
                s += __shfl_xor(s, 8, 16); s += __shfl_xor(s, 4, 16);
                s += __shfl_xor(s, 2, 16); s += __shfl_xor(s, 1, 16);
                if (l == 0) out[OUT_CLS + b * 10 + j] = s + bj;
            }
        }
        __syncthreads();
        if (tid < 64) scores[tid] += noise[tid];
        __syncthreads();
        if (tid < Bn) {
            int b = tid;
            float best = -1e30f; int bi = 0;
            for (int u = 0; u < Un; ++u) {
                float v = scores[b * Un + u];
                if (v > best) { best = v; bi = u; }
            }
            float best2 = -1e30f; int bi2 = 0;
            for (int u = 0; u < Un; ++u) {
                if (u == bi) continue;
                float v = scores[b * Un + u];
                if (v > best2) { best2 = v; bi2 = u; }
            }
            topi[b * 2] = bi;
            topi[b * 2 + 1] = bi2;
            ((int*)ws)[WS_TOPI + b * 2] = bi;
            ((int*)ws)[WS_TOPI + b * 2 + 1] = bi2;
            out[OUT_TOPI + b * 2] = (float)bi;
            out[OUT_TOPI + b * 2 + 1] = (float)bi2;
        }
        __syncthreads();
        if (tid == 0) {
            int cnt[Un];
            for (int u = 0; u < Un; ++u) cnt[u] = 0;
            for (int i = 0; i < Bn * 2; ++i) cnt[topi[i]]++;
            float lb = 0.f;
            for (int u = 0; u < Un; ++u) {
                float d = (float)cnt[u] * (1.f / 16.f) - 0.125f;
                lb += d * d;
            }
            out[OUT_LB] = lb * (1.f / Un);
            float l2 = 0.f;
            #pragma unroll
            for (int i = 0; i < 12; ++i) l2 += sqrtf(ws[WS_L2P + i]);
            out[OUT_L2] = 0.01f * l2;
        }
        if (tid < Bn) {
            int b2 = tid;
            int s0 = topi[b2 * 2], s1 = topi[b2 * 2 + 1];
            float lg[Un];
            for (int u2 = 0; u2 < Un; ++u2) lg[u2] = ws[WS_BSUM + u2] * (1.0f / Cn);
            lg[s0] += ws[WS_GSUM + b2 * 8 + s0] * (1.0f / (Cn * HWn));
            lg[s1] += ws[WS_GSUM + b2 * 8 + s1] * (1.0f / (Cn * HWn));
            float m = -1e30f;
            for (int u2 = 0; u2 < Un; ++u2) m = fmaxf(m, lg[u2]);
            float den = 0.f, e[Un];
            for (int u2 = 0; u2 < Un; ++u2) { e[u2] = expf(lg[u2] - m); den += e[u2]; }
            float inv = 1.0f / den;
            for (int u2 = 0; u2 < Un; ++u2) {
                gate[b2 * Un + u2] = e[u2] * inv;
                ws[WS_GATE + b2 * Un + u2] = e[u2] * inv;
            }
            ws[WS_GSEL + b2 * 2] = gate[b2 * Un + s0];
            ws[WS_GSEL + b2 * 2 + 1] = gate[b2 * Un + s1];
        }
    }
    grid_bar(bar, 4);

    // ---- stage F: blocks 0-3: biasc (1024 elems, 1/thread) ----
    if (bid < 4) {
        int i = bid * 256 + tid;
        int b2 = i >> 7, c = i & 127;
        float s = 0.f;
        #pragma unroll
        for (int u2 = 0; u2 < Un; ++u2)
            s = fmaf(ws[WS_GATE + b2 * Un + u2], cb[u2 * Cn + c], s);
        ws[WS_BIASC + i] = s;
    }
}

// -------- kernel 3: gate-combined weights -> bf16 [b][cout][tap][cin] ------
__global__ __launch_bounds__(256) void wprep_kernel(const float* __restrict__ cw,
                                                    float* __restrict__ ws) {
    int bid = blockIdx.x;            // 256 blocks
    int b = bid >> 5, g = bid & 31;
    const int* topi = (const int*)ws + WS_TOPI;
    int u0 = topi[b * 2], u1 = topi[b * 2 + 1];
    float g0 = ws[WS_GSEL + b * 2], g1 = ws[WS_GSEL + b * 2 + 1];
    __shared__ float lds[1152];
    unsigned short* wc = (unsigned short*)(ws + WS_WCOMB);
    int tid = threadIdx.x;
    for (int co = 0; co < 4; ++co) {
        int cout = g * 4 + co;
        const float* r0 = cw + ((size_t)u0 * 128 + cout) * 1152;
        const float* r1 = cw + ((size_t)u1 * 128 + cout) * 1152;
        if (co) __syncthreads();
        #pragma unroll
        for (int i = 0; i < 5; ++i) {
            int e = tid + i * 256;
            if (e < 1152) lds[e] = g0 * r0[e] + g1 * r1[e];
        }
        __syncthreads();
        #pragma unroll
        for (int i = 0; i < 3; ++i) {
            int p = tid + i * 256;           // 576 = 9 taps x 64 cin-pairs
            if (p < 576) {
                int tap = p >> 6, cp = p & 63;
                unsigned lo = f2bf(lds[(2 * cp) * 9 + tap]);
                unsigned hi = f2bf(lds[(2 * cp + 1) * 9 + tap]);
                *(unsigned*)(wc + ((((size_t)(b * 128 + cout) * 9 + tap) << 7)
                                   + 2 * cp)) = lo | (hi << 16);
            }
        }
    }
}

// -------- kernel 4: MFMA implicit-GEMM conv + gated combine ----------------
__global__ __launch_bounds__(128) void conv_mfma_kernel(
    const float* __restrict__ wsf, float* __restrict__ out) {
    const unsigned short* __restrict__ xt = (const unsigned short*)(wsf + WS_XT);
    const unsigned short* __restrict__ wc = (const unsigned short*)(wsf + WS_WCOMB);

    int bid = blockIdx.x;
    int b = bid >> 6, y = bid & 63;
    int tid = threadIdx.x;
    int wave = tid >> 6, lane = tid & 63;
    int quad = lane >> 4, l15 = lane & 15;
    int m0 = wave << 6;

    // 198 px x 136 shorts (272 B stride: 256 B data + 16 B pad)
    __shared__ __align__(16) unsigned short xs[198 * 136];

    f32x4 acc[4][4];
    #pragma unroll
    for (int mt = 0; mt < 4; ++mt)
        #pragma unroll
        for (int nt = 0; nt < 4; ++nt)
            acc[mt][nt] = (f32x4){0.f, 0.f, 0.f, 0.f};

    #pragma unroll
    for (int i = 0; i < 25; ++i) {
        int o = tid + i * 128;
        if (o < 3168) {
            int px = o >> 4, part = o & 15;
            int r3 = (unsigned)px / 66u;
            int col = px - r3 * 66;
            int ry = y + r3 - 1;
            int gx = col - 1;
            uint4 v = {0u, 0u, 0u, 0u};
            if ((unsigned)ry < 64u && (unsigned)gx < 64u) {
                v = *(const uint4*)(xt +
                    ((((size_t)b * 64 + ry) * 64 + gx) << 7) + (part << 3));
            }
            *(uint4*)((char*)xs + px * 272 + part * 16) = v;
        }
    }
    __syncthreads();

    int ldsrd = l15 * 272 + quad * 16;
    #pragma unroll
    for (int tap = 0; tap < 9; ++tap) {
        const int dy = tap / 3, dx = tap % 3;
        #pragma unroll
        for (int chunk = 0; chunk < 4; ++chunk) {
            bf16x8 af[4];
            #pragma unroll
            for (int mt = 0; mt < 4; ++mt) {
                int cout = m0 + mt * 16 + l15;
                af[mt] = *(const bf16x8*)(wc +
                    (((size_t)(b * 128 + cout) * 9 + tap) << 7) +
                    (chunk << 5) + (quad << 3));
            }
            bf16x8 bfr[4];
            #pragma unroll
            for (int nt = 0; nt < 4; ++nt) {
                int off = (dy * 66 + dx + nt * 16) * 272 + (chunk << 6);
                bfr[nt] = *(const bf16x8*)((char*)xs + ldsrd + off);
            }
            #pragma unroll
            for (int mt = 0; mt < 4; ++mt)
                #pragma unroll
                for (int nt = 0; nt < 4; ++nt)
                    acc[mt][nt] = __builtin_amdgcn_mfma_f32_16x16x32_bf16(
                        af[mt], bfr[nt], acc[mt][nt], 0, 0, 0);
        }
    }

    #pragma unroll
    for (int mt = 0; mt < 4; ++mt) {
        #pragma unroll
        for (int r = 0; r < 4; ++r) {
            int c = m0 + mt * 16 + (quad << 2) + r;
            float bias = wsf[WS_BIASC + (b << 7) + c];
            size_t rowb = (((size_t)b * 128 + c) << 12) + (y << 6);
            #pragma unroll
            for (int nt = 0; nt < 4; ++nt)
                out[rowb + nt * 16 + l15] = acc[mt][nt][r] + bias;
        }
    }
}

extern "C" void kernel_launch(void* const* d_in, const int* in_sizes, int n_in,
                              void* d_out, int out_size, void* d_ws, size_t ws_size,
                              hipStream_t stream) {
    const float* x  = (const float*)d_in[0];
    const float* W1 = (const float*)d_in[1];
    const float* b1 = (const float*)d_in[2];
    const float* W2 = (const float*)d_in[3];
    const float* b2 = (const float*)d_in[4];
    const float* W3 = (const float*)d_in[5];
    const float* b3 = (const float*)d_in[6];
    const float* W4 = (const float*)d_in[7];
    const float* b4 = (const float*)d_in[8];
    const float* Wu = (const float*)d_in[9];
    const float* bu = (const float*)d_in[10];
    const float* Wc = (const float*)d_in[11];
    const float* bc = (const float*)d_in[12];
    const float* cw = (const float*)d_in[13];
    const float* cb = (const float*)d_in[14];
    float* out = (float*)d_out;
    float* ws  = (float*)d_ws;

    prep_kernel<<<1612, 256, 0, stream>>>(x, cw, W1, b1, W2, b2, W3, b3,
                                          W4, b4, Wu, bu, Wc, bc, ws);
    router_fused_kernel<<<RGRID, 256, 0, stream>>>(W1, b1, W2, b2, W3, b3,
                                                   W4, b4, Wu, bu, Wc, bc,
                                                   cb, ws, out);
    wprep_kernel<<<256, 256, 0, stream>>>(cw, ws);
    conv_mfma_kernel<<<512, 128, 0, stream>>>(ws, out);
}

// Round 9
// 166.416 us; speedup vs baseline: 1.2252x; 1.2252x over previous
//
#include <hip/hip_runtime.h>
#include <math.h>

// Problem constants
#define Bn   8
#define Cn   128
#define Hn   64
#define Wn   64
#define HWn  4096
#define Un   8
#define Ln   10
#define HIDn 128

// d_out layout (float offsets): final, cls_logits, l2_reg, top_i, lb_loss
#define OUT_FINAL 0
#define OUT_CLS   4194304
#define OUT_L2    4194384
#define OUT_TOPI  4194385
#define OUT_LB    4194401

// ws layout (float offsets)
#define WS_POOLED 0                      // [1024]
#define WS_STR    1024                   // [1024*9] S,R0,R63,C0,C63,c00,c0r,cb0,cbr
#define WS_TOPI   10240                  // int[16]
#define WS_GSEL   10256                  // [16]
#define WS_BIASC  10272                  // [1024]
#define WS_L2P    11296                  // [12]
#define WS_GSUM   11308                  // [64]
#define WS_BSUM   11372                  // [8]
#define WS_FLAGS  11380                  // unsigned[64] gsum done-flags
#define WS_PACK   11444                  // fp32 pack[46][256][4] = 47104 floats
#define WS_W9P    58548                  // [64][1152] w9 partials
#define WS_XT     132276                 // bf16 xt[8][64][64][128]
#define WS_WCOMB  2229428                // bf16 wcomb[8][128][9][128]

#define NOISE_PARTITIONABLE 1

typedef __attribute__((ext_vector_type(8))) short bf16x8;
typedef __attribute__((ext_vector_type(4))) float f32x4;

__device__ __forceinline__ unsigned short f2bf(float f) {
    unsigned u = __float_as_uint(f);
    unsigned r = (u + 0x7fffu + ((u >> 16) & 1u)) >> 16;
    return (unsigned short)r;
}

// ---------------- jax threefry2x32 noise (key=42, shape (8,8)) --------------
__device__ __forceinline__ unsigned rotl32(unsigned x, int d) {
    return (x << d) | (x >> (32 - d));
}

__device__ __forceinline__ void threefry2x32(unsigned k1, unsigned k2,
                                             unsigned c0, unsigned c1,
                                             unsigned* o0, unsigned* o1) {
    unsigned ks0 = k1, ks1 = k2, ks2 = k1 ^ k2 ^ 0x1BD11BDAu;
    unsigned ksa[3] = {ks0, ks1, ks2};
    const int rot[2][4] = {{13, 15, 26, 6}, {17, 29, 16, 24}};
    unsigned x0 = c0 + ks0, x1 = c1 + ks1;
    #pragma unroll
    for (int s = 0; s < 5; ++s) {
        #pragma unroll
        for (int q = 0; q < 4; ++q) {
            x0 += x1;
            x1 = rotl32(x1, rot[s & 1][q]);
            x1 ^= x0;
        }
        x0 += ksa[(s + 1) % 3];
        x1 += ksa[(s + 2) % 3] + (unsigned)(s + 1);
    }
    *o0 = x0;
    *o1 = x1;
}

__device__ float jax_noise_elem(int i) {
    unsigned o0, o1, bits;
#if NOISE_PARTITIONABLE
    threefry2x32(0u, 42u, 0u, (unsigned)i, &o0, &o1);
    bits = o0 ^ o1;
#else
    {
        int second = (i >= 32);
        unsigned j = (unsigned)(second ? i - 32 : i);
        threefry2x32(0u, 42u, j, j + 32u, &o0, &o1);
        bits = second ? o1 : o0;
    }
#endif
    unsigned fb = (bits >> 9) | 0x3f800000u;
    float f = __uint_as_float(fb) - 1.0f;
    const float lo = __uint_as_float(0xBF7FFFFFu);
    float u = f * (1.0f - lo) + lo;
    u = fmaxf(lo, u);
    float w = -log1pf(-u * u);
    float p;
    if (w < 5.0f) {
        w = w - 2.5f;
        p = 2.81022636e-08f;
        p = fmaf(p, w, 3.43273939e-07f);
        p = fmaf(p, w, -3.5233877e-06f);
        p = fmaf(p, w, -4.39150654e-06f);
        p = fmaf(p, w, 0.00021858087f);
        p = fmaf(p, w, -0.00125372503f);
        p = fmaf(p, w, -0.00417768164f);
        p = fmaf(p, w, 0.246640727f);
        p = fmaf(p, w, 1.50140941f);
    } else {
        w = sqrtf(w) - 3.0f;
        p = -0.000200214257f;
        p = fmaf(p, w, 0.000100950558f);
        p = fmaf(p, w, 0.00134934322f);
        p = fmaf(p, w, -0.00367342844f);
        p = fmaf(p, w, 0.00573950773f);
        p = fmaf(p, w, -0.0076224613f);
        p = fmaf(p, w, 0.00943887047f);
        p = fmaf(p, w, 1.00167406f);
        p = fmaf(p, w, 2.83297682f);
    }
    float n = 1.41421356237309515f * (p * u);
    return n * 0.01f;
}

// -- kernel 1: xprep(512) + pool(1024) + w9(64) + l2(12) + wpack(46) --------
__global__ __launch_bounds__(256) void prep_kernel(
    const float* __restrict__ x, const float* __restrict__ cw,
    const float* __restrict__ W1, const float* __restrict__ b1,
    const float* __restrict__ W2, const float* __restrict__ b2,
    const float* __restrict__ W3, const float* __restrict__ b3,
    const float* __restrict__ W4, const float* __restrict__ b4,
    const float* __restrict__ Wu, const float* __restrict__ bu,
    const float* __restrict__ Wc, const float* __restrict__ bc,
    float* __restrict__ ws) {
    __shared__ float smem[8256];
    int bid = blockIdx.x;
    int tid = threadIdx.x;

    if (bid < 512) {
        // ---- x transpose to channel-last bf16: xt[b][y][x][cin] ----
        int b = bid >> 6, y = bid & 63;
        #pragma unroll
        for (int k = 0; k < 32; ++k) {
            int cin = (tid >> 6) + (k << 2);
            int xcol = tid & 63;
            smem[xcol * 129 + cin] =
                x[(((size_t)b * 128 + cin) << 12) + (y << 6) + xcol];
        }
        __syncthreads();
        unsigned short* xtp = (unsigned short*)(ws + WS_XT);
        #pragma unroll
        for (int i = 0; i < 4; ++i) {
            int op = tid + (i << 8);
            int px = op >> 4, part = op & 15;
            const float* src = smem + px * 129 + part * 8;
            uint4 u;
            u.x = (unsigned)f2bf(src[0]) | ((unsigned)f2bf(src[1]) << 16);
            u.y = (unsigned)f2bf(src[2]) | ((unsigned)f2bf(src[3]) << 16);
            u.z = (unsigned)f2bf(src[4]) | ((unsigned)f2bf(src[5]) << 16);
            u.w = (unsigned)f2bf(src[6]) | ((unsigned)f2bf(src[7]) << 16);
            *(uint4*)(xtp + (((((size_t)b * 64 + y) * 64 + px) << 7) + (part << 3))) = u;
        }
    } else if (bid < 1536) {
        // ---- avg pool + border strips + corners per (b,cin) ----
        int bc_ = bid - 512;
        const float4* p4 = (const float4*)(x + (size_t)bc_ * HWn);
        float vals[5] = {0.f, 0.f, 0.f, 0.f, 0.f};  // S,R0,R63,C0,C63
        #pragma unroll
        for (int it = 0; it < 4; ++it) {
            int i = tid + it * 256;
            float4 v = p4[i];
            float s4 = v.x + v.y + v.z + v.w;
            vals[0] += s4;
            if (i < 16) vals[1] += s4;
            if (i >= 1008) vals[2] += s4;
            if ((i & 15) == 0) vals[3] += v.x;
            if ((i & 15) == 15) vals[4] += v.w;
            if (i == 0) ws[WS_STR + bc_ * 9 + 5] = v.x;
            if (i == 15) ws[WS_STR + bc_ * 9 + 6] = v.w;
            if (i == 1008) ws[WS_STR + bc_ * 9 + 7] = v.x;
            if (i == 1023) ws[WS_STR + bc_ * 9 + 8] = v.w;
        }
        #pragma unroll
        for (int q = 0; q < 5; ++q)
            #pragma unroll
            for (int off = 32; off > 0; off >>= 1)
                vals[q] += __shfl_xor(vals[q], off);
        int wave = tid >> 6, lane = tid & 63;
        if (lane == 0) {
            #pragma unroll
            for (int q = 0; q < 5; ++q) smem[wave * 5 + q] = vals[q];
        }
        __syncthreads();
        if (tid < 5) {
            float o = smem[tid] + smem[5 + tid] + smem[10 + tid] + smem[15 + tid];
            ws[WS_STR + bc_ * 9 + tid] = o;
            if (tid == 0) ws[WS_POOLED + bc_] = o * (1.0f / HWn);
        }
    } else if (bid < 1600) {
        // ---- w9 partials: block (u,g) sums couts g*16..g*16+15 ----
        int idx = bid - 1536;
        int u = idx >> 3, g = idx & 7;
        if (idx == 0 && tid < 64) ((unsigned*)(ws + WS_FLAGS))[tid] = 0u;
        const float* base = cw + (size_t)u * 147456 + (size_t)g * 18432;
        float a0 = 0.f, a1 = 0.f, a2 = 0.f, a3 = 0.f, a4 = 0.f;
        #pragma unroll
        for (int cout = 0; cout < 16; ++cout) {
            const float* row = base + (size_t)cout * 1152;
            a0 += row[tid];
            a1 += row[tid + 256];
            a2 += row[tid + 512];
            a3 += row[tid + 768];
            if (tid < 128) a4 += row[tid + 1024];
        }
        float* dst = ws + WS_W9P + (size_t)idx * 1152;
        dst[tid] = a0;
        dst[tid + 256] = a1;
        dst[tid + 512] = a2;
        dst[tid + 768] = a3;
        if (tid < 128) dst[tid + 1024] = a4;
    } else if (bid < 1612) {
        // ---- l2 sumsq partials for the 12 router params ----
        int idx = bid - 1600;
        const float* ptab[12] = {W1, b1, W2, b2, W3, b3, W4, b4, Wu, bu, Wc, bc};
        const int ntab[12] = {16384, 128, 16384, 128, 8192, 64, 4096, 64, 512, 8, 640, 10};
        const float* p = ptab[idx];
        int n = ntab[idx];
        float s = 0.f;
        for (int i = tid; i < n; i += 256) { float v = p[i]; s = fmaf(v, v, s); }
        #pragma unroll
        for (int off = 32; off > 0; off >>= 1) s += __shfl_xor(s, off);
        int wave = tid >> 6, lane = tid & 63;
        if (lane == 0) smem[wave] = s;
        __syncthreads();
        if (tid == 0) ws[WS_L2P + idx] = smem[0] + smem[1] + smem[2] + smem[3];
    } else {
        // ---- weight pack: slice i, thread-interleaved fp32 (bit-exact) ----
        // router thread t's i-th float4 at pack[(i*256+t)*4] -> coalesced burst
        int i = bid - 1612;
        int t = tid;
        const float* src = nullptr;
        if (i < 16)      src = W1 + (t >> 1) * 128 + (t & 1) * 64 + i * 4;
        else if (i < 32) src = W2 + (t >> 1) * 128 + (t & 1) * 64 + (i - 16) * 4;
        else if (i < 40) src = W3 + (t >> 2) * 128 + (t & 3) * 32 + (i - 32) * 4;
        else if (i < 44) src = W4 + (t >> 2) * 64 + (t & 3) * 16 + (i - 40) * 4;
        else if (i == 44) { if (t < 128) src = Wu + (t >> 4) * 64 + (t & 15) * 4; }
        else              { if (t < 160) src = Wc + (t >> 4) * 64 + (t & 15) * 4; }
        float4 v = {0.f, 0.f, 0.f, 0.f};
        if (src) v = *(const float4*)src;
        *(float4*)&ws[WS_PACK + ((i << 8) + t) * 4] = v;
    }
}

// -- kernel 2: router (65 blocks): 0-63 gsum (flag on done), 64 = full MLP --
// mega-block preloads all 184 KB of packed weights into registers via 46
// independent coalesced loads (burst, latency-hidden) -- kills R6's 2.8 GB/s
// serialized single-CU fetch without R8's 8us-per-grid-barrier cost
__global__ __launch_bounds__(256, 1) void router_fused_kernel(
    const float* __restrict__ b1, const float* __restrict__ b2,
    const float* __restrict__ b3, const float* __restrict__ b4,
    const float* __restrict__ bu, const float* __restrict__ bc,
    const float* __restrict__ cb,
    float* __restrict__ ws, float* __restrict__ out) {
    __shared__ float sh[4304];
    int bid = blockIdx.x;
    int tid = threadIdx.x;
    unsigned* flags = (unsigned*)(ws + WS_FLAGS);

    if (bid < 64) {
        // ---- gsum[b][u] (+ bsum for blocks 0-7), then release flag ----
        int b = bid >> 3, u = bid & 7;
        float* T = sh;
        float* red = sh + 1152;
        if (tid < 128) {
            const float* st = ws + WS_STR + (b * 128 + tid) * 9;
            float S = st[0], R0 = st[1], R63 = st[2], C0 = st[3], C63 = st[4];
            float c00 = st[5], c0r = st[6], cb0 = st[7], cbr = st[8];
            float Rex[3] = {R63, 0.f, R0};
            float Cex[3] = {C63, 0.f, C0};
            float crn[3][3] = {{cbr, 0.f, cb0}, {0.f, 0.f, 0.f}, {c0r, 0.f, c00}};
            #pragma unroll
            for (int ky = 0; ky < 3; ++ky)
                #pragma unroll
                for (int kx = 0; kx < 3; ++kx)
                    T[tid * 9 + ky * 3 + kx] = S - Rex[ky] - Cex[kx] + crn[ky][kx];
        }
        __syncthreads();
        float s = 0.f;
        #pragma unroll
        for (int g = 0; g < 8; ++g) {
            const float* row = ws + WS_W9P + (size_t)((u << 3) + g) * 1152;
            #pragma unroll
            for (int i = 0; i < 4; ++i)
                s = fmaf(row[tid + i * 256], T[tid + i * 256], s);
            if (tid < 128) s = fmaf(row[tid + 1024], T[tid + 1024], s);
        }
        #pragma unroll
        for (int off = 32; off > 0; off >>= 1) s += __shfl_xor(s, off);
        int wave = tid >> 6, lane = tid & 63;
        if (lane == 0) red[wave] = s;
        __syncthreads();
        float bs = 0.f;
        if (b == 0) {
            float t2 = (tid < 128) ? cb[u * 128 + tid] : 0.f;
            #pragma unroll
            for (int off = 32; off > 0; off >>= 1) t2 += __shfl_xor(t2, off);
            if (lane == 0) red[4 + wave] = t2;
        }
        __syncthreads();
        if (tid == 0) {
            ws[WS_GSUM + bid] = red[0] + red[1] + red[2] + red[3];
            if (b == 0) ws[WS_BSUM + u] = red[4] + red[5] + red[6] + red[7];
            __hip_atomic_store(&flags[bid], 1u, __ATOMIC_RELEASE,
                               __HIP_MEMORY_SCOPE_AGENT);
        }
        (void)bs;
        return;
    }

    // ---- mega block: whole router in one block ----
    float4 wr[46];
    #pragma unroll
    for (int i = 0; i < 46; ++i)
        wr[i] = *(const float4*)&ws[WS_PACK + ((i << 8) + tid) * 4];

    float* pooled = sh;          // 1024
    float* h1 = sh + 1024;       // 1024
    float* h2 = sh + 2048;       // 1024
    float* h3 = sh + 3072;       // 512
    float* feat = sh + 3584;     // 512
    float* scores = sh + 4096;   // 64
    float* noise = sh + 4160;    // 64
    float* gate = sh + 4224;     // 64
    int* topi = (int*)(sh + 4288);

    for (int i = tid; i < 1024; i += 256) pooled[i] = ws[WS_POOLED + i];
    __syncthreads();

    // L1: row = tid>>1, k-half = tid&1
    {
        int row = tid >> 1, h = tid & 1;
        float bj = b1[row];
        #pragma unroll
        for (int b = 0; b < 8; ++b) {
            float s = 0.f;
            #pragma unroll
            for (int i = 0; i < 16; ++i) {
                float4 xv = *(float4*)&pooled[b * 128 + h * 64 + i * 4];
                s += wr[i].x * xv.x + wr[i].y * xv.y + wr[i].z * xv.z + wr[i].w * xv.w;
            }
            s += __shfl_xor(s, 1);
            if (h == 0) h1[b * 128 + row] = fmaxf(s + bj, 0.f);
        }
    }
    __syncthreads();
    // L2
    {
        int row = tid >> 1, h = tid & 1;
        float bj = b2[row];
        #pragma unroll
        for (int b = 0; b < 8; ++b) {
            float s = 0.f;
            #pragma unroll
            for (int i = 0; i < 16; ++i) {
                float4 xv = *(float4*)&h1[b * 128 + h * 64 + i * 4];
                s += wr[16 + i].x * xv.x + wr[16 + i].y * xv.y
                   + wr[16 + i].z * xv.z + wr[16 + i].w * xv.w;
            }
            s += __shfl_xor(s, 1);
            if (h == 0) h2[b * 128 + row] = fmaxf(s + bj, 0.f);
        }
    }
    __syncthreads();
    // L3: row = tid>>2, quarter = tid&3
    {
        int row = tid >> 2, q = tid & 3;
        float bj = b3[row];
        #pragma unroll
        for (int b = 0; b < 8; ++b) {
            float s = 0.f;
            #pragma unroll
            for (int i = 0; i < 8; ++i) {
                float4 xv = *(float4*)&h2[b * 128 + q * 32 + i * 4];
                s += wr[32 + i].x * xv.x + wr[32 + i].y * xv.y
                   + wr[32 + i].z * xv.z + wr[32 + i].w * xv.w;
            }
            s += __shfl_xor(s, 1);
            s += __shfl_xor(s, 2);
            if (q == 0) h3[b * 64 + row] = fmaxf(s + bj, 0.f);
        }
    }
    __syncthreads();
    // L4: no relu
    {
        int row = tid >> 2, q = tid & 3;
        float bj = b4[row];
        #pragma unroll
        for (int b = 0; b < 8; ++b) {
            float s = 0.f;
            #pragma unroll
            for (int i = 0; i < 4; ++i) {
                float4 xv = *(float4*)&h3[b * 64 + q * 16 + i * 4];
                s += wr[40 + i].x * xv.x + wr[40 + i].y * xv.y
                   + wr[40 + i].z * xv.z + wr[40 + i].w * xv.w;
            }
            s += __shfl_xor(s, 1);
            s += __shfl_xor(s, 2);
            if (q == 0) feat[b * 64 + row] = s + bj;
        }
    }
    __syncthreads();
    if (tid < 64) noise[tid] = jax_noise_elem(tid);
    // scores: threads 0-127: u = tid>>4
    if (tid < 128) {
        int u = tid >> 4, l16 = tid & 15;
        float bj = bu[u];
        #pragma unroll
        for (int b = 0; b < 8; ++b) {
            float4 xv = *(float4*)&feat[b * 64 + l16 * 4];
            float s = wr[44].x * xv.x + wr[44].y * xv.y
                    + wr[44].z * xv.z + wr[44].w * xv.w;
            s += __shfl_xor(s, 1); s += __shfl_xor(s, 2);
            s += __shfl_xor(s, 4); s += __shfl_xor(s, 8);
            if (l16 == 0) scores[b * 8 + u] = s + bj;
        }
    }
    // cls logits: threads 0-159: row = tid>>4
    if (tid < 160) {
        int r = tid >> 4, l16 = tid & 15;
        float bj = bc[r];
        #pragma unroll
        for (int b = 0; b < 8; ++b) {
            float4 xv = *(float4*)&feat[b * 64 + l16 * 4];
            float s = wr[45].x * xv.x + wr[45].y * xv.y
                    + wr[45].z * xv.z + wr[45].w * xv.w;
            s += __shfl_xor(s, 1); s += __shfl_xor(s, 2);
            s += __shfl_xor(s, 4); s += __shfl_xor(s, 8);
            if (l16 == 0) out[OUT_CLS + b * 10 + r] = s + bj;
        }
    }
    __syncthreads();
    if (tid < 64) scores[tid] += noise[tid];
    __syncthreads();
    if (tid < Bn) {
        int b = tid;
        float best = -1e30f; int bi = 0;
        for (int u = 0; u < Un; ++u) {
            float v = scores[b * Un + u];
            if (v > best) { best = v; bi = u; }
        }
        float best2 = -1e30f; int bi2 = 0;
        for (int u = 0; u < Un; ++u) {
            if (u == bi) continue;
            float v = scores[b * Un + u];
            if (v > best2) { best2 = v; bi2 = u; }
        }
        topi[b * 2] = bi;
        topi[b * 2 + 1] = bi2;
        ((int*)ws)[WS_TOPI + b * 2] = bi;
        ((int*)ws)[WS_TOPI + b * 2 + 1] = bi2;
        out[OUT_TOPI + b * 2] = (float)bi;
        out[OUT_TOPI + b * 2 + 1] = (float)bi2;
    }
    __syncthreads();
    if (tid == 0) {
        int cnt[Un];
        for (int u = 0; u < Un; ++u) cnt[u] = 0;
        for (int i = 0; i < Bn * 2; ++i) cnt[topi[i]]++;
        float lb = 0.f;
        for (int u = 0; u < Un; ++u) {
            float d = (float)cnt[u] * (1.f / 16.f) - 0.125f;
            lb += d * d;
        }
        out[OUT_LB] = lb * (1.f / Un);
        float l2 = 0.f;
        #pragma unroll
        for (int i = 0; i < 12; ++i) l2 += sqrtf(ws[WS_L2P + i]);
        out[OUT_L2] = 0.01f * l2;
    }
    // ---- wait for gsum producers (one-directional, no full barrier) ----
    if (tid < 64) {
        while (__hip_atomic_load(&flags[tid], __ATOMIC_RELAXED,
                                 __HIP_MEMORY_SCOPE_AGENT) == 0u)
            __builtin_amdgcn_s_sleep(2);
    }
    __syncthreads();
    __builtin_amdgcn_fence(__ATOMIC_ACQUIRE, "agent");
    // ---- gate softmax + gsel + biasc ----
    if (tid < Bn) {
        int b2 = tid;
        int s0 = topi[b2 * 2], s1 = topi[b2 * 2 + 1];
        float lg[Un];
        for (int u2 = 0; u2 < Un; ++u2) lg[u2] = ws[WS_BSUM + u2] * (1.0f / Cn);
        lg[s0] += ws[WS_GSUM + b2 * 8 + s0] * (1.0f / (Cn * HWn));
        lg[s1] += ws[WS_GSUM + b2 * 8 + s1] * (1.0f / (Cn * HWn));
        float m = -1e30f;
        for (int u2 = 0; u2 < Un; ++u2) m = fmaxf(m, lg[u2]);
        float den = 0.f, e[Un];
        for (int u2 = 0; u2 < Un; ++u2) { e[u2] = expf(lg[u2] - m); den += e[u2]; }
        float inv = 1.0f / den;
        for (int u2 = 0; u2 < Un; ++u2) gate[b2 * Un + u2] = e[u2] * inv;
        ws[WS_GSEL + b2 * 2] = gate[b2 * Un + s0];
        ws[WS_GSEL + b2 * 2 + 1] = gate[b2 * Un + s1];
    }
    __syncthreads();
    for (int i = tid; i < 1024; i += 256) {
        int b2 = i >> 7, c = i & 127;
        float s = 0.f;
        #pragma unroll
        for (int u2 = 0; u2 < Un; ++u2)
            s = fmaf(gate[b2 * Un + u2], cb[u2 * Cn + c], s);
        ws[WS_BIASC + i] = s;
    }
}

// -------- kernel 3: gate-combined weights -> bf16 [b][cout][tap][cin] ------
__global__ __launch_bounds__(256) void wprep_kernel(const float* __restrict__ cw,
                                                    float* __restrict__ ws) {
    int bid = blockIdx.x;            // 256 blocks
    int b = bid >> 5, g = bid & 31;
    const int* topi = (const int*)ws + WS_TOPI;
    int u0 = topi[b * 2], u1 = topi[b * 2 + 1];
    float g0 = ws[WS_GSEL + b * 2], g1 = ws[WS_GSEL + b * 2 + 1];
    __shared__ float lds[1152];
    unsigned short* wc = (unsigned short*)(ws + WS_WCOMB);
    int tid = threadIdx.x;
    for (int co = 0; co < 4; ++co) {
        int cout = g * 4 + co;
        const float* r0 = cw + ((size_t)u0 * 128 + cout) * 1152;
        const float* r1 = cw + ((size_t)u1 * 128 + cout) * 1152;
        if (co) __syncthreads();
        #pragma unroll
        for (int i = 0; i < 5; ++i) {
            int e = tid + i * 256;
            if (e < 1152) lds[e] = g0 * r0[e] + g1 * r1[e];
        }
        __syncthreads();
        #pragma unroll
        for (int i = 0; i < 3; ++i) {
            int p = tid + i * 256;           // 576 = 9 taps x 64 cin-pairs
            if (p < 576) {
                int tap = p >> 6, cp = p & 63;
                unsigned lo = f2bf(lds[(2 * cp) * 9 + tap]);
                unsigned hi = f2bf(lds[(2 * cp + 1) * 9 + tap]);
                *(unsigned*)(wc + ((((size_t)(b * 128 + cout) * 9 + tap) << 7)
                                   + 2 * cp)) = lo | (hi << 16);
            }
        }
    }
}

// -------- kernel 4: MFMA implicit-GEMM conv + gated combine ----------------
__global__ __launch_bounds__(128) void conv_mfma_kernel(
    const float* __restrict__ wsf, float* __restrict__ out) {
    const unsigned short* __restrict__ xt = (const unsigned short*)(wsf + WS_XT);
    const unsigned short* __restrict__ wc = (const unsigned short*)(wsf + WS_WCOMB);

    int bid = blockIdx.x;
    int b = bid >> 6, y = bid & 63;
    int tid = threadIdx.x;
    int wave = tid >> 6, lane = tid & 63;
    int quad = lane >> 4, l15 = lane & 15;
    int m0 = wave << 6;

    // 198 px x 136 shorts (272 B stride: 256 B data + 16 B pad)
    __shared__ __align__(16) unsigned short xs[198 * 136];

    f32x4 acc[4][4];
    #pragma unroll
    for (int mt = 0; mt < 4; ++mt)
        #pragma unroll
        for (int nt = 0; nt < 4; ++nt)
            acc[mt][nt] = (f32x4){0.f, 0.f, 0.f, 0.f};

    #pragma unroll
    for (int i = 0; i < 25; ++i) {
        int o = tid + i * 128;
        if (o < 3168) {
            int px = o >> 4, part = o & 15;
            int r3 = (unsigned)px / 66u;
            int col = px - r3 * 66;
            int ry = y + r3 - 1;
            int gx = col - 1;
            uint4 v = {0u, 0u, 0u, 0u};
            if ((unsigned)ry < 64u && (unsigned)gx < 64u) {
                v = *(const uint4*)(xt +
                    ((((size_t)b * 64 + ry) * 64 + gx) << 7) + (part << 3));
            }
            *(uint4*)((char*)xs + px * 272 + part * 16) = v;
        }
    }
    __syncthreads();

    int ldsrd = l15 * 272 + quad * 16;
    #pragma unroll
    for (int tap = 0; tap < 9; ++tap) {
        const int dy = tap / 3, dx = tap % 3;
        #pragma unroll
        for (int chunk = 0; chunk < 4; ++chunk) {
            bf16x8 af[4];
            #pragma unroll
            for (int mt = 0; mt < 4; ++mt) {
                int cout = m0 + mt * 16 + l15;
                af[mt] = *(const bf16x8*)(wc +
                    (((size_t)(b * 128 + cout) * 9 + tap) << 7) +
                    (chunk << 5) + (quad << 3));
            }
            bf16x8 bfr[4];
            #pragma unroll
            for (int nt = 0; nt < 4; ++nt) {
                int off = (dy * 66 + dx + nt * 16) * 272 + (chunk << 6);
                bfr[nt] = *(const bf16x8*)((char*)xs + ldsrd + off);
            }
            #pragma unroll
            for (int mt = 0; mt < 4; ++mt)
                #pragma unroll
                for (int nt = 0; nt < 4; ++nt)
                    acc[mt][nt] = __builtin_amdgcn_mfma_f32_16x16x32_bf16(
                        af[mt], bfr[nt], acc[mt][nt], 0, 0, 0);
        }
    }

    #pragma unroll
    for (int mt = 0; mt < 4; ++mt) {
        #pragma unroll
        for (int r = 0; r < 4; ++r) {
            int c = m0 + mt * 16 + (quad << 2) + r;
            float bias = wsf[WS_BIASC + (b << 7) + c];
            size_t rowb = (((size_t)b * 128 + c) << 12) + (y << 6);
            #pragma unroll
            for (int nt = 0; nt < 4; ++nt)
                out[rowb + nt * 16 + l15] = acc[mt][nt][r] + bias;
        }
    }
}

extern "C" void kernel_launch(void* const* d_in, const int* in_sizes, int n_in,
                              void* d_out, int out_size, void* d_ws, size_t ws_size,
                              hipStream_t stream) {
    const float* x  = (const float*)d_in[0];
    const float* W1 = (const float*)d_in[1];
    const float* b1 = (const float*)d_in[2];
    const float* W2 = (const float*)d_in[3];
    const float* b2 = (const float*)d_in[4];
    const float* W3 = (const float*)d_in[5];
    const float* b3 = (const float*)d_in[6];
    const float* W4 = (const float*)d_in[7];
    const float* b4 = (const float*)d_in[8];
    const float* Wu = (const float*)d_in[9];
    const float* bu = (const float*)d_in[10];
    const float* Wc = (const float*)d_in[11];
    const float* bc = (const float*)d_in[12];
    const float* cw = (const float*)d_in[13];
    const float* cb = (const float*)d_in[14];
    float* out = (float*)d_out;
    float* ws  = (float*)d_ws;

    prep_kernel<<<1658, 256, 0, stream>>>(x, cw, W1, b1, W2, b2, W3, b3,
                                          W4, b4, Wu, bu, Wc, bc, ws);
    router_fused_kernel<<<65, 256, 0, stream>>>(b1, b2, b3, b4, bu, bc,
                                                cb, ws, out);
    wprep_kernel<<<256, 256, 0, stream>>>(cw, ws);
    conv_mfma_kernel<<<512, 128, 0, stream>>>(ws, out);
}

// Round 10
// 163.615 us; speedup vs baseline: 1.2462x; 1.0171x over previous
//
#include <hip/hip_runtime.h>
#include <math.h>

// Problem constants
#define Bn   8
#define Cn   128
#define Hn   64
#define Wn   64
#define HWn  4096
#define Un   8
#define Ln   10
#define HIDn 128

// d_out layout (float offsets): final, cls_logits, l2_reg, top_i, lb_loss
#define OUT_FINAL 0
#define OUT_CLS   4194304
#define OUT_L2    4194384
#define OUT_TOPI  4194385
#define OUT_LB    4194401

// ws layout (float offsets)
#define WS_POOLED 0                      // [1024]
#define WS_STR    1024                   // [1024*9] S,R0,R63,C0,C63,c00,c0r,cb0,cbr
#define WS_TOPI   10240                  // int[16]
#define WS_GSEL   10256                  // [16]
#define WS_BIASC  10272                  // [1024]
#define WS_L2P    11296                  // [12]
#define WS_GSUM   11308                  // [64]
#define WS_BSUM   11372                  // [8]
#define WS_FLAGS  11380                  // unsigned[64] gsum done-flags
#define WS_PACK   11444                  // fp32 pack[46][256][4] = 47104 floats
#define WS_W9P    58548                  // [64][1152] w9 partials
#define WS_XT     132276                 // bf16 xt[8][64][64][128]
#define WS_WCOMB  2229428                // bf16 wcomb[8][128][9][128]

#define NOISE_PARTITIONABLE 1

typedef __attribute__((ext_vector_type(8))) short bf16x8;
typedef __attribute__((ext_vector_type(4))) float f32x4;

__device__ __forceinline__ unsigned short f2bf(float f) {
    unsigned u = __float_as_uint(f);
    unsigned r = (u + 0x7fffu + ((u >> 16) & 1u)) >> 16;
    return (unsigned short)r;
}

// ---------------- jax threefry2x32 noise (key=42, shape (8,8)) --------------
__device__ __forceinline__ unsigned rotl32(unsigned x, int d) {
    return (x << d) | (x >> (32 - d));
}

__device__ __forceinline__ void threefry2x32(unsigned k1, unsigned k2,
                                             unsigned c0, unsigned c1,
                                             unsigned* o0, unsigned* o1) {
    unsigned ks0 = k1, ks1 = k2, ks2 = k1 ^ k2 ^ 0x1BD11BDAu;
    unsigned ksa[3] = {ks0, ks1, ks2};
    const int rot[2][4] = {{13, 15, 26, 6}, {17, 29, 16, 24}};
    unsigned x0 = c0 + ks0, x1 = c1 + ks1;
    #pragma unroll
    for (int s = 0; s < 5; ++s) {
        #pragma unroll
        for (int q = 0; q < 4; ++q) {
            x0 += x1;
            x1 = rotl32(x1, rot[s & 1][q]);
            x1 ^= x0;
        }
        x0 += ksa[(s + 1) % 3];
        x1 += ksa[(s + 2) % 3] + (unsigned)(s + 1);
    }
    *o0 = x0;
    *o1 = x1;
}

__device__ float jax_noise_elem(int i) {
    unsigned o0, o1, bits;
#if NOISE_PARTITIONABLE
    threefry2x32(0u, 42u, 0u, (unsigned)i, &o0, &o1);
    bits = o0 ^ o1;
#else
    {
        int second = (i >= 32);
        unsigned j = (unsigned)(second ? i - 32 : i);
        threefry2x32(0u, 42u, j, j + 32u, &o0, &o1);
        bits = second ? o1 : o0;
    }
#endif
    unsigned fb = (bits >> 9) | 0x3f800000u;
    float f = __uint_as_float(fb) - 1.0f;
    const float lo = __uint_as_float(0xBF7FFFFFu);
    float u = f * (1.0f - lo) + lo;
    u = fmaxf(lo, u);
    float w = -log1pf(-u * u);
    float p;
    if (w < 5.0f) {
        w = w - 2.5f;
        p = 2.81022636e-08f;
        p = fmaf(p, w, 3.43273939e-07f);
        p = fmaf(p, w, -3.5233877e-06f);
        p = fmaf(p, w, -4.39150654e-06f);
        p = fmaf(p, w, 0.00021858087f);
        p = fmaf(p, w, -0.00125372503f);
        p = fmaf(p, w, -0.00417768164f);
        p = fmaf(p, w, 0.246640727f);
        p = fmaf(p, w, 1.50140941f);
    } else {
        w = sqrtf(w) - 3.0f;
        p = -0.000200214257f;
        p = fmaf(p, w, 0.000100950558f);
        p = fmaf(p, w, 0.00134934322f);
        p = fmaf(p, w, -0.00367342844f);
        p = fmaf(p, w, 0.00573950773f);
        p = fmaf(p, w, -0.0076224613f);
        p = fmaf(p, w, 0.00943887047f);
        p = fmaf(p, w, 1.00167406f);
        p = fmaf(p, w, 2.83297682f);
    }
    float n = 1.41421356237309515f * (p * u);
    return n * 0.01f;
}

// -- kernel 1: xprep(512) + pool(1024) + w9(64) + l2(12) + wpack(46) --------
__global__ __launch_bounds__(256) void prep_kernel(
    const float* __restrict__ x, const float* __restrict__ cw,
    const float* __restrict__ W1, const float* __restrict__ b1,
    const float* __restrict__ W2, const float* __restrict__ b2,
    const float* __restrict__ W3, const float* __restrict__ b3,
    const float* __restrict__ W4, const float* __restrict__ b4,
    const float* __restrict__ Wu, const float* __restrict__ bu,
    const float* __restrict__ Wc, const float* __restrict__ bc,
    float* __restrict__ ws) {
    __shared__ float smem[8256];
    int bid = blockIdx.x;
    int tid = threadIdx.x;

    if (bid < 512) {
        // ---- x transpose to channel-last bf16: xt[b][y][x][cin] ----
        int b = bid >> 6, y = bid & 63;
        #pragma unroll
        for (int k = 0; k < 32; ++k) {
            int cin = (tid >> 6) + (k << 2);
            int xcol = tid & 63;
            smem[xcol * 129 + cin] =
                x[(((size_t)b * 128 + cin) << 12) + (y << 6) + xcol];
        }
        __syncthreads();
        unsigned short* xtp = (unsigned short*)(ws + WS_XT);
        #pragma unroll
        for (int i = 0; i < 4; ++i) {
            int op = tid + (i << 8);
            int px = op >> 4, part = op & 15;
            const float* src = smem + px * 129 + part * 8;
            uint4 u;
            u.x = (unsigned)f2bf(src[0]) | ((unsigned)f2bf(src[1]) << 16);
            u.y = (unsigned)f2bf(src[2]) | ((unsigned)f2bf(src[3]) << 16);
            u.z = (unsigned)f2bf(src[4]) | ((unsigned)f2bf(src[5]) << 16);
            u.w = (unsigned)f2bf(src[6]) | ((unsigned)f2bf(src[7]) << 16);
            *(uint4*)(xtp + (((((size_t)b * 64 + y) * 64 + px) << 7) + (part << 3))) = u;
        }
    } else if (bid < 1536) {
        // ---- avg pool + border strips + corners per (b,cin) ----
        int bc_ = bid - 512;
        const float4* p4 = (const float4*)(x + (size_t)bc_ * HWn);
        float vals[5] = {0.f, 0.f, 0.f, 0.f, 0.f};  // S,R0,R63,C0,C63
        #pragma unroll
        for (int it = 0; it < 4; ++it) {
            int i = tid + it * 256;
            float4 v = p4[i];
            float s4 = v.x + v.y + v.z + v.w;
            vals[0] += s4;
            if (i < 16) vals[1] += s4;
            if (i >= 1008) vals[2] += s4;
            if ((i & 15) == 0) vals[3] += v.x;
            if ((i & 15) == 15) vals[4] += v.w;
            if (i == 0) ws[WS_STR + bc_ * 9 + 5] = v.x;
            if (i == 15) ws[WS_STR + bc_ * 9 + 6] = v.w;
            if (i == 1008) ws[WS_STR + bc_ * 9 + 7] = v.x;
            if (i == 1023) ws[WS_STR + bc_ * 9 + 8] = v.w;
        }
        #pragma unroll
        for (int q = 0; q < 5; ++q)
            #pragma unroll
            for (int off = 32; off > 0; off >>= 1)
                vals[q] += __shfl_xor(vals[q], off);
        int wave = tid >> 6, lane = tid & 63;
        if (lane == 0) {
            #pragma unroll
            for (int q = 0; q < 5; ++q) smem[wave * 5 + q] = vals[q];
        }
        __syncthreads();
        if (tid < 5) {
            float o = smem[tid] + smem[5 + tid] + smem[10 + tid] + smem[15 + tid];
            ws[WS_STR + bc_ * 9 + tid] = o;
            if (tid == 0) ws[WS_POOLED + bc_] = o * (1.0f / HWn);
        }
    } else if (bid < 1600) {
        // ---- w9 partials: block (u,g) sums couts g*16..g*16+15 ----
        int idx = bid - 1536;
        int u = idx >> 3, g = idx & 7;
        if (idx == 0 && tid < 64) ((unsigned*)(ws + WS_FLAGS))[tid] = 0u;
        const float* base = cw + (size_t)u * 147456 + (size_t)g * 18432;
        float a0 = 0.f, a1 = 0.f, a2 = 0.f, a3 = 0.f, a4 = 0.f;
        #pragma unroll
        for (int cout = 0; cout < 16; ++cout) {
            const float* row = base + (size_t)cout * 1152;
            a0 += row[tid];
            a1 += row[tid + 256];
            a2 += row[tid + 512];
            a3 += row[tid + 768];
            if (tid < 128) a4 += row[tid + 1024];
        }
        float* dst = ws + WS_W9P + (size_t)idx * 1152;
        dst[tid] = a0;
        dst[tid + 256] = a1;
        dst[tid + 512] = a2;
        dst[tid + 768] = a3;
        if (tid < 128) dst[tid + 1024] = a4;
    } else if (bid < 1612) {
        // ---- l2 sumsq partials for the 12 router params ----
        int idx = bid - 1600;
        const float* ptab[12] = {W1, b1, W2, b2, W3, b3, W4, b4, Wu, bu, Wc, bc};
        const int ntab[12] = {16384, 128, 16384, 128, 8192, 64, 4096, 64, 512, 8, 640, 10};
        const float* p = ptab[idx];
        int n = ntab[idx];
        float s = 0.f;
        for (int i = tid; i < n; i += 256) { float v = p[i]; s = fmaf(v, v, s); }
        #pragma unroll
        for (int off = 32; off > 0; off >>= 1) s += __shfl_xor(s, off);
        int wave = tid >> 6, lane = tid & 63;
        if (lane == 0) smem[wave] = s;
        __syncthreads();
        if (tid == 0) ws[WS_L2P + idx] = smem[0] + smem[1] + smem[2] + smem[3];
    } else {
        // ---- weight pack: slice i, thread-interleaved fp32 (bit-exact) ----
        int i = bid - 1612;
        int t = tid;
        const float* src = nullptr;
        if (i < 16)      src = W1 + (t >> 1) * 128 + (t & 1) * 64 + i * 4;
        else if (i < 32) src = W2 + (t >> 1) * 128 + (t & 1) * 64 + (i - 16) * 4;
        else if (i < 40) src = W3 + (t >> 2) * 128 + (t & 3) * 32 + (i - 32) * 4;
        else if (i < 44) src = W4 + (t >> 2) * 64 + (t & 3) * 16 + (i - 40) * 4;
        else if (i == 44) { if (t < 128) src = Wu + (t >> 4) * 64 + (t & 15) * 4; }
        else              { if (t < 160) src = Wc + (t >> 4) * 64 + (t & 15) * 4; }
        float4 v = {0.f, 0.f, 0.f, 0.f};
        if (src) v = *(const float4*)src;
        *(float4*)&ws[WS_PACK + ((i << 8) + t) * 4] = v;
    }
}

// -- kernel 2: router (65 blocks): 0-63 gsum (flag on done), 64 = full MLP --
__global__ __launch_bounds__(256, 1) void router_fused_kernel(
    const float* __restrict__ b1, const float* __restrict__ b2,
    const float* __restrict__ b3, const float* __restrict__ b4,
    const float* __restrict__ bu, const float* __restrict__ bc,
    const float* __restrict__ cb,
    float* __restrict__ ws, float* __restrict__ out) {
    __shared__ float sh[4304];
    int bid = blockIdx.x;
    int tid = threadIdx.x;
    unsigned* flags = (unsigned*)(ws + WS_FLAGS);

    if (bid < 64) {
        // ---- gsum[b][u] (+ bsum for blocks 0-7), then release flag ----
        int b = bid >> 3, u = bid & 7;
        float* T = sh;
        float* red = sh + 1152;
        if (tid < 128) {
            const float* st = ws + WS_STR + (b * 128 + tid) * 9;
            float S = st[0], R0 = st[1], R63 = st[2], C0 = st[3], C63 = st[4];
            float c00 = st[5], c0r = st[6], cb0 = st[7], cbr = st[8];
            float Rex[3] = {R63, 0.f, R0};
            float Cex[3] = {C63, 0.f, C0};
            float crn[3][3] = {{cbr, 0.f, cb0}, {0.f, 0.f, 0.f}, {c0r, 0.f, c00}};
            #pragma unroll
            for (int ky = 0; ky < 3; ++ky)
                #pragma unroll
                for (int kx = 0; kx < 3; ++kx)
                    T[tid * 9 + ky * 3 + kx] = S - Rex[ky] - Cex[kx] + crn[ky][kx];
        }
        __syncthreads();
        float s = 0.f;
        #pragma unroll
        for (int g = 0; g < 8; ++g) {
            const float* row = ws + WS_W9P + (size_t)((u << 3) + g) * 1152;
            #pragma unroll
            for (int i = 0; i < 4; ++i)
                s = fmaf(row[tid + i * 256], T[tid + i * 256], s);
            if (tid < 128) s = fmaf(row[tid + 1024], T[tid + 1024], s);
        }
        #pragma unroll
        for (int off = 32; off > 0; off >>= 1) s += __shfl_xor(s, off);
        int wave = tid >> 6, lane = tid & 63;
        if (lane == 0) red[wave] = s;
        __syncthreads();
        if (b == 0) {
            float t2 = (tid < 128) ? cb[u * 128 + tid] : 0.f;
            #pragma unroll
            for (int off = 32; off > 0; off >>= 1) t2 += __shfl_xor(t2, off);
            if (lane == 0) red[4 + wave] = t2;
        }
        __syncthreads();
        if (tid == 0) {
            ws[WS_GSUM + bid] = red[0] + red[1] + red[2] + red[3];
            if (b == 0) ws[WS_BSUM + u] = red[4] + red[5] + red[6] + red[7];
            __hip_atomic_store(&flags[bid], 1u, __ATOMIC_RELEASE,
                               __HIP_MEMORY_SCOPE_AGENT);
        }
        return;
    }

    // ---- mega block: whole router in one block ----
    float4 wr[46];
    #pragma unroll
    for (int i = 0; i < 46; ++i)
        wr[i] = *(const float4*)&ws[WS_PACK + ((i << 8) + tid) * 4];

    float* pooled = sh;          // 1024
    float* h1 = sh + 1024;       // 1024
    float* h2 = sh + 2048;       // 1024
    float* h3 = sh + 3072;       // 512
    float* feat = sh + 3584;     // 512
    float* scores = sh + 4096;   // 64
    float* noise = sh + 4160;    // 64
    float* gate = sh + 4224;     // 64
    int* topi = (int*)(sh + 4288);

    for (int i = tid; i < 1024; i += 256) pooled[i] = ws[WS_POOLED + i];
    __syncthreads();

    // L1: row = tid>>1, k-half = tid&1
    {
        int row = tid >> 1, h = tid & 1;
        float bj = b1[row];
        #pragma unroll
        for (int b = 0; b < 8; ++b) {
            float s = 0.f;
            #pragma unroll
            for (int i = 0; i < 16; ++i) {
                float4 xv = *(float4*)&pooled[b * 128 + h * 64 + i * 4];
                s += wr[i].x * xv.x + wr[i].y * xv.y + wr[i].z * xv.z + wr[i].w * xv.w;
            }
            s += __shfl_xor(s, 1);
            if (h == 0) h1[b * 128 + row] = fmaxf(s + bj, 0.f);
        }
    }
    __syncthreads();
    // L2
    {
        int row = tid >> 1, h = tid & 1;
        float bj = b2[row];
        #pragma unroll
        for (int b = 0; b < 8; ++b) {
            float s = 0.f;
            #pragma unroll
            for (int i = 0; i < 16; ++i) {
                float4 xv = *(float4*)&h1[b * 128 + h * 64 + i * 4];
                s += wr[16 + i].x * xv.x + wr[16 + i].y * xv.y
                   + wr[16 + i].z * xv.z + wr[16 + i].w * xv.w;
            }
            s += __shfl_xor(s, 1);
            if (h == 0) h2[b * 128 + row] = fmaxf(s + bj, 0.f);
        }
    }
    __syncthreads();
    // L3: row = tid>>2, quarter = tid&3
    {
        int row = tid >> 2, q = tid & 3;
        float bj = b3[row];
        #pragma unroll
        for (int b = 0; b < 8; ++b) {
            float s = 0.f;
            #pragma unroll
            for (int i = 0; i < 8; ++i) {
                float4 xv = *(float4*)&h2[b * 128 + q * 32 + i * 4];
                s += wr[32 + i].x * xv.x + wr[32 + i].y * xv.y
                   + wr[32 + i].z * xv.z + wr[32 + i].w * xv.w;
            }
            s += __shfl_xor(s, 1);
            s += __shfl_xor(s, 2);
            if (q == 0) h3[b * 64 + row] = fmaxf(s + bj, 0.f);
        }
    }
    __syncthreads();
    // L4: no relu
    {
        int row = tid >> 2, q = tid & 3;
        float bj = b4[row];
        #pragma unroll
        for (int b = 0; b < 8; ++b) {
            float s = 0.f;
            #pragma unroll
            for (int i = 0; i < 4; ++i) {
                float4 xv = *(float4*)&h3[b * 64 + q * 16 + i * 4];
                s += wr[40 + i].x * xv.x + wr[40 + i].y * xv.y
                   + wr[40 + i].z * xv.z + wr[40 + i].w * xv.w;
            }
            s += __shfl_xor(s, 1);
            s += __shfl_xor(s, 2);
            if (q == 0) feat[b * 64 + row] = s + bj;
        }
    }
    __syncthreads();
    if (tid < 64) noise[tid] = jax_noise_elem(tid);
    if (tid < 128) {
        int u = tid >> 4, l16 = tid & 15;
        float bj = bu[u];
        #pragma unroll
        for (int b = 0; b < 8; ++b) {
            float4 xv = *(float4*)&feat[b * 64 + l16 * 4];
            float s = wr[44].x * xv.x + wr[44].y * xv.y
                    + wr[44].z * xv.z + wr[44].w * xv.w;
            s += __shfl_xor(s, 1); s += __shfl_xor(s, 2);
            s += __shfl_xor(s, 4); s += __shfl_xor(s, 8);
            if (l16 == 0) scores[b * 8 + u] = s + bj;
        }
    }
    if (tid < 160) {
        int r = tid >> 4, l16 = tid & 15;
        float bj = bc[r];
        #pragma unroll
        for (int b = 0; b < 8; ++b) {
            float4 xv = *(float4*)&feat[b * 64 + l16 * 4];
            float s = wr[45].x * xv.x + wr[45].y * xv.y
                    + wr[45].z * xv.z + wr[45].w * xv.w;
            s += __shfl_xor(s, 1); s += __shfl_xor(s, 2);
            s += __shfl_xor(s, 4); s += __shfl_xor(s, 8);
            if (l16 == 0) out[OUT_CLS + b * 10 + r] = s + bj;
        }
    }
    __syncthreads();
    if (tid < 64) scores[tid] += noise[tid];
    __syncthreads();
    if (tid < Bn) {
        int b = tid;
        float best = -1e30f; int bi = 0;
        for (int u = 0; u < Un; ++u) {
            float v = scores[b * Un + u];
            if (v > best) { best = v; bi = u; }
        }
        float best2 = -1e30f; int bi2 = 0;
        for (int u = 0; u < Un; ++u) {
            if (u == bi) continue;
            float v = scores[b * Un + u];
            if (v > best2) { best2 = v; bi2 = u; }
        }
        topi[b * 2] = bi;
        topi[b * 2 + 1] = bi2;
        ((int*)ws)[WS_TOPI + b * 2] = bi;
        ((int*)ws)[WS_TOPI + b * 2 + 1] = bi2;
        out[OUT_TOPI + b * 2] = (float)bi;
        out[OUT_TOPI + b * 2 + 1] = (float)bi2;
    }
    __syncthreads();
    if (tid == 0) {
        int cnt[Un];
        for (int u = 0; u < Un; ++u) cnt[u] = 0;
        for (int i = 0; i < Bn * 2; ++i) cnt[topi[i]]++;
        float lb = 0.f;
        for (int u = 0; u < Un; ++u) {
            float d = (float)cnt[u] * (1.f / 16.f) - 0.125f;
            lb += d * d;
        }
        out[OUT_LB] = lb * (1.f / Un);
        float l2 = 0.f;
        #pragma unroll
        for (int i = 0; i < 12; ++i) l2 += sqrtf(ws[WS_L2P + i]);
        out[OUT_L2] = 0.01f * l2;
    }
    // ---- wait for gsum producers (one-directional, no full barrier) ----
    if (tid < 64) {
        while (__hip_atomic_load(&flags[tid], __ATOMIC_RELAXED,
                                 __HIP_MEMORY_SCOPE_AGENT) == 0u)
            __builtin_amdgcn_s_sleep(2);
    }
    __syncthreads();
    __builtin_amdgcn_fence(__ATOMIC_ACQUIRE, "agent");
    // ---- gate softmax + gsel + biasc ----
    if (tid < Bn) {
        int b2 = tid;
        int s0 = topi[b2 * 2], s1 = topi[b2 * 2 + 1];
        float lg[Un];
        for (int u2 = 0; u2 < Un; ++u2) lg[u2] = ws[WS_BSUM + u2] * (1.0f / Cn);
        lg[s0] += ws[WS_GSUM + b2 * 8 + s0] * (1.0f / (Cn * HWn));
        lg[s1] += ws[WS_GSUM + b2 * 8 + s1] * (1.0f / (Cn * HWn));
        float m = -1e30f;
        for (int u2 = 0; u2 < Un; ++u2) m = fmaxf(m, lg[u2]);
        float den = 0.f, e[Un];
        for (int u2 = 0; u2 < Un; ++u2) { e[u2] = expf(lg[u2] - m); den += e[u2]; }
        float inv = 1.0f / den;
        for (int u2 = 0; u2 < Un; ++u2) gate[b2 * Un + u2] = e[u2] * inv;
        ws[WS_GSEL + b2 * 2] = gate[b2 * Un + s0];
        ws[WS_GSEL + b2 * 2 + 1] = gate[b2 * Un + s1];
    }
    __syncthreads();
    for (int i = tid; i < 1024; i += 256) {
        int b2 = i >> 7, c = i & 127;
        float s = 0.f;
        #pragma unroll
        for (int u2 = 0; u2 < Un; ++u2)
            s = fmaf(gate[b2 * Un + u2], cb[u2 * Cn + c], s);
        ws[WS_BIASC + i] = s;
    }
}

// -------- kernel 3: gate-combined weights -> bf16 [b][cout][tap][cin] ------
__global__ __launch_bounds__(256) void wprep_kernel(const float* __restrict__ cw,
                                                    float* __restrict__ ws) {
    int bid = blockIdx.x;            // 256 blocks
    int b = bid >> 5, g = bid & 31;
    const int* topi = (const int*)ws + WS_TOPI;
    int u0 = topi[b * 2], u1 = topi[b * 2 + 1];
    float g0 = ws[WS_GSEL + b * 2], g1 = ws[WS_GSEL + b * 2 + 1];
    __shared__ float lds[1152];
    unsigned short* wc = (unsigned short*)(ws + WS_WCOMB);
    int tid = threadIdx.x;
    for (int co = 0; co < 4; ++co) {
        int cout = g * 4 + co;
        const float* r0 = cw + ((size_t)u0 * 128 + cout) * 1152;
        const float* r1 = cw + ((size_t)u1 * 128 + cout) * 1152;
        if (co) __syncthreads();
        #pragma unroll
        for (int i = 0; i < 5; ++i) {
            int e = tid + i * 256;
            if (e < 1152) lds[e] = g0 * r0[e] + g1 * r1[e];
        }
        __syncthreads();
        #pragma unroll
        for (int i = 0; i < 3; ++i) {
            int p = tid + i * 256;           // 576 = 9 taps x 64 cin-pairs
            if (p < 576) {
                int tap = p >> 6, cp = p & 63;
                unsigned lo = f2bf(lds[(2 * cp) * 9 + tap]);
                unsigned hi = f2bf(lds[(2 * cp + 1) * 9 + tap]);
                *(unsigned*)(wc + ((((size_t)(b * 128 + cout) * 9 + tap) << 7)
                                   + 2 * cp)) = lo | (hi << 16);
            }
        }
    }
}

// -------- kernel 4: MFMA conv, K-split across 4 waves ----------------------
// 256 thr = 4 waves: (cout-half h, chunk-pair p). Same LDS (2 blocks/CU) but
// 2 waves/SIMD instead of 1 (R9 ran 128 thr = 1 wave/SIMD: no latency hiding
// for the global-A + ds_read + MFMA mix). Partial-K acc reduced through xs.
__global__ __launch_bounds__(256) void conv_mfma_kernel(
    const float* __restrict__ wsf, float* __restrict__ out) {
    const unsigned short* __restrict__ xt = (const unsigned short*)(wsf + WS_XT);
    const unsigned short* __restrict__ wc = (const unsigned short*)(wsf + WS_WCOMB);

    int bid = blockIdx.x;
    int b = bid >> 6, y = bid & 63;
    int tid = threadIdx.x;
    int wave = tid >> 6, lane = tid & 63;
    int quad = lane >> 4, l15 = lane & 15;
    int h = wave & 1, p = wave >> 1;
    int m0 = h << 6;

    // 198 px x 136 shorts (272 B stride: 256 B data + 16 B pad)
    __shared__ __align__(16) unsigned short xs[198 * 136];

    f32x4 acc[4][4];
    #pragma unroll
    for (int mt = 0; mt < 4; ++mt)
        #pragma unroll
        for (int nt = 0; nt < 4; ++nt)
            acc[mt][nt] = (f32x4){0.f, 0.f, 0.f, 0.f};

    #pragma unroll
    for (int i = 0; i < 13; ++i) {
        int o = tid + i * 256;
        if (o < 3168) {
            int px = o >> 4, part = o & 15;
            int r3 = (unsigned)px / 66u;
            int col = px - r3 * 66;
            int ry = y + r3 - 1;
            int gx = col - 1;
            uint4 v = {0u, 0u, 0u, 0u};
            if ((unsigned)ry < 64u && (unsigned)gx < 64u) {
                v = *(const uint4*)(xt +
                    ((((size_t)b * 64 + ry) * 64 + gx) << 7) + (part << 3));
            }
            *(uint4*)((char*)xs + px * 272 + part * 16) = v;
        }
    }
    __syncthreads();

    int ldsrd = l15 * 272 + quad * 16;
    #pragma unroll
    for (int c2 = 0; c2 < 2; ++c2) {
        int chunk = p * 2 + c2;
        #pragma unroll
        for (int tap = 0; tap < 9; ++tap) {
            const int dy = tap / 3, dx = tap % 3;
            bf16x8 af[4];
            #pragma unroll
            for (int mt = 0; mt < 4; ++mt) {
                int cout = m0 + mt * 16 + l15;
                af[mt] = *(const bf16x8*)(wc +
                    (((size_t)(b * 128 + cout) * 9 + tap) << 7) +
                    (chunk << 5) + (quad << 3));
            }
            bf16x8 bfr[4];
            #pragma unroll
            for (int nt = 0; nt < 4; ++nt) {
                int off = (dy * 66 + dx + nt * 16) * 272 + (chunk << 6);
                bfr[nt] = *(const bf16x8*)((char*)xs + ldsrd + off);
            }
            #pragma unroll
            for (int mt = 0; mt < 4; ++mt)
                #pragma unroll
                for (int nt = 0; nt < 4; ++nt)
                    acc[mt][nt] = __builtin_amdgcn_mfma_f32_16x16x32_bf16(
                        af[mt], bfr[nt], acc[mt][nt], 0, 0, 0);
        }
    }

    // ---- cross-wave K reduction through xs (re-used after barrier) ----
    __syncthreads();
    if (wave >= 2) {
        char* dst = (char*)xs + h * 17408 + lane * 272;
        #pragma unroll
        for (int mt = 0; mt < 4; ++mt)
            #pragma unroll
            for (int nt = 0; nt < 4; ++nt)
                *(f32x4*)(dst + (mt * 4 + nt) * 16) = acc[mt][nt];
    }
    __syncthreads();
    if (wave < 2) {
        const char* src = (const char*)xs + h * 17408 + lane * 272;
        #pragma unroll
        for (int mt = 0; mt < 4; ++mt)
            #pragma unroll
            for (int nt = 0; nt < 4; ++nt) {
                f32x4 v = *(const f32x4*)(src + (mt * 4 + nt) * 16);
                acc[mt][nt].x += v.x; acc[mt][nt].y += v.y;
                acc[mt][nt].z += v.z; acc[mt][nt].w += v.w;
            }
        #pragma unroll
        for (int mt = 0; mt < 4; ++mt) {
            #pragma unroll
            for (int r = 0; r < 4; ++r) {
                int c = m0 + mt * 16 + (quad << 2) + r;
                float bias = wsf[WS_BIASC + (b << 7) + c];
                size_t rowb = (((size_t)b * 128 + c) << 12) + (y << 6);
                #pragma unroll
                for (int nt = 0; nt < 4; ++nt)
                    out[rowb + nt * 16 + l15] = acc[mt][nt][r] + bias;
            }
        }
    }
}

extern "C" void kernel_launch(void* const* d_in, const int* in_sizes, int n_in,
                              void* d_out, int out_size, void* d_ws, size_t ws_size,
                              hipStream_t stream) {
    const float* x  = (const float*)d_in[0];
    const float* W1 = (const float*)d_in[1];
    const float* b1 = (const float*)d_in[2];
    const float* W2 = (const float*)d_in[3];
    const float* b2 = (const float*)d_in[4];
    const float* W3 = (const float*)d_in[5];
    const float* b3 = (const float*)d_in[6];
    const float* W4 = (const float*)d_in[7];
    const float* b4 = (const float*)d_in[8];
    const float* Wu = (const float*)d_in[9];
    const float* bu = (const float*)d_in[10];
    const float* Wc = (const float*)d_in[11];
    const float* bc = (const float*)d_in[12];
    const float* cw = (const float*)d_in[13];
    const float* cb = (const float*)d_in[14];
    float* out = (float*)d_out;
    float* ws  = (float*)d_ws;

    prep_kernel<<<1658, 256, 0, stream>>>(x, cw, W1, b1, W2, b2, W3, b3,
                                          W4, b4, Wu, bu, Wc, bc, ws);
    router_fused_kernel<<<65, 256, 0, stream>>>(b1, b2, b3, b4, bu, bc,
                                                cb, ws, out);
    wprep_kernel<<<256, 256, 0, stream>>>(cw, ws);
    conv_mfma_kernel<<<512, 256, 0, stream>>>(ws, out);
}